// Round 1
// baseline (505.499 us; speedup 1.0000x reference)
//
#include <hip/hip_runtime.h>
#include <hip/hip_bf16.h>
#include <stdint.h>

// Problem constants: B=128, T=256, C=768, D=768. M_total = 32768.

typedef __attribute__((ext_vector_type(8))) short short8;   // 8 x bf16 (4 VGPRs)
typedef __attribute__((ext_vector_type(4))) short short4v;  // 4 x bf16 (8B)
typedef __attribute__((ext_vector_type(4))) float f32x4;

__device__ __forceinline__ short f2bf(float f) {
    uint32_t u = __float_as_uint(f);
    u += 0x7fffu + ((u >> 16) & 1u);   // RNE
    return (short)(u >> 16);
}
__device__ __forceinline__ float bf2f(short s) {
    return __uint_as_float(((uint32_t)(uint16_t)s) << 16);
}

// ---------------------------------------------------------------------------
// x fp32 -> bf16  (25,165,824 elements, 4/thread)
__global__ __launch_bounds__(256) void cvt_x(const float* __restrict__ x,
                                             short* __restrict__ xb) {
    long i = ((long)blockIdx.x * 256 + threadIdx.x) * 4;
    f32x4 v = *(const f32x4*)(x + i);
    short4v o;
    o.x = f2bf(v.x); o.y = f2bf(v.y); o.z = f2bf(v.z); o.w = f2bf(v.w);
    *(short4v*)(xb + i) = o;
}

// W [768,768] fp32 -> Wt [768,768] bf16 transposed (Wt[d][c] = W[c][d])
__global__ __launch_bounds__(256) void cvt_wt(const float* __restrict__ W,
                                              short* __restrict__ Wt) {
    __shared__ float tile[32][33];
    int d0 = blockIdx.x * 32, c0 = blockIdx.y * 32;
    int tr = threadIdx.x >> 5, tc = threadIdx.x & 31;
    #pragma unroll
    for (int i = 0; i < 32; i += 8)
        tile[tr + i][tc] = W[(long)(c0 + tr + i) * 768 + d0 + tc];
    __syncthreads();
    #pragma unroll
    for (int i = 0; i < 32; i += 8)
        Wt[(long)(d0 + tr + i) * 768 + c0 + tc] = f2bf(tile[tc][tr + i]);
}

// ---------------------------------------------------------------------------
// Generic bf16 GEMM, C = A (M x K, row-major) * B^T (B stored N x K row-major)
// 128x128 block tile, BK=32, 4 waves (2x2), 16x16x32 MFMA, global_load_lds.
// EPI 0: bf16 row-major store   (q, k)
// EPI 1: bf16 per-batch-transposed store for v:  vt[b][col][row&255]
// EPI 2: fp32 row-major store, scaled  (S and final out)
template <int EPI>
__global__ __launch_bounds__(256)
void gemm_bt(const short* __restrict__ A, const short* __restrict__ B,
             void* __restrict__ C, int M, int N, int K,
             long sA, long sB, long sC, float scale) {
    __shared__ short lA[128 * 32];
    __shared__ short lB[128 * 32];
    const int bz = blockIdx.z;
    const short* Ab = A + (long)bz * sA;
    const short* Bb = B + (long)bz * sB;
    const int m0 = blockIdx.y * 128;
    const int n0 = blockIdx.x * 128;
    const int tid = threadIdx.x;
    const int w = tid >> 6, lane = tid & 63;
    const int wm = (w >> 1) * 64;   // wave tile origin within block
    const int wn = (w & 1) * 64;
    const int lrow = lane >> 2;           // staging: row within 16-row segment
    const int lcol = (lane & 3) * 8;      // staging: k offset (8 bf16 = 16B)

    f32x4 acc[4][4] = {};

    for (int k0 = 0; k0 < K; k0 += 32) {
        // ---- stage A,B tiles into LDS (async, 16B/lane, wave-uniform base)
        #pragma unroll
        for (int c2 = 0; c2 < 2; ++c2) {
            int seg = c2 * 4 + w;                 // 0..7 -> 16 rows each
            int row = seg * 16 + lrow;
            const short* ga = Ab + (long)(m0 + row) * K + k0 + lcol;
            __builtin_amdgcn_global_load_lds(
                (const __attribute__((address_space(1))) void*)ga,
                (__attribute__((address_space(3))) void*)(lA + seg * 512),
                16, 0, 0);
            const short* gb = Bb + (long)(n0 + row) * K + k0 + lcol;
            __builtin_amdgcn_global_load_lds(
                (const __attribute__((address_space(1))) void*)gb,
                (__attribute__((address_space(3))) void*)(lB + seg * 512),
                16, 0, 0);
        }
        __syncthreads();

        // ---- fragments + MFMA
        short8 af[4], bfr[4];
        const int ar = wm + (lane & 15);
        const int br = wn + (lane & 15);
        const int kq = (lane >> 4) * 8;
        #pragma unroll
        for (int tmi = 0; tmi < 4; ++tmi)
            af[tmi] = *(const short8*)(lA + (ar + tmi * 16) * 32 + kq);
        #pragma unroll
        for (int tni = 0; tni < 4; ++tni)
            bfr[tni] = *(const short8*)(lB + (br + tni * 16) * 32 + kq);
        #pragma unroll
        for (int tmi = 0; tmi < 4; ++tmi)
            #pragma unroll
            for (int tni = 0; tni < 4; ++tni)
                acc[tmi][tni] = __builtin_amdgcn_mfma_f32_16x16x32_bf16(
                    af[tmi], bfr[tni], acc[tmi][tni], 0, 0, 0);
        __syncthreads();
    }

    // ---- epilogue; C/D layout: col = lane&15, row = (lane>>4)*4 + r
    const int r0 = wm + (lane >> 4) * 4;
    const int c0 = wn + (lane & 15);
    #pragma unroll
    for (int tmi = 0; tmi < 4; ++tmi)
        #pragma unroll
        for (int tni = 0; tni < 4; ++tni)
            #pragma unroll
            for (int r = 0; r < 4; ++r) {
                int row = m0 + r0 + tmi * 16 + r;
                int col = n0 + c0 + tni * 16;
                float val = acc[tmi][tni][r] * scale;
                if (EPI == 0) {
                    ((short*)C)[(long)bz * sC + (long)row * N + col] = f2bf(val);
                } else if (EPI == 1) {
                    // v transposed per batch: vt[b][d][t], b=row>>8, t=row&255
                    ((short*)C)[((long)(row >> 8) * 768 + col) * 256 + (row & 255)] = f2bf(val);
                } else {
                    ((float*)C)[(long)bz * sC + (long)row * N + col] = val;
                }
            }
}

// ---------------------------------------------------------------------------
// In-place RoPE on q and k (bf16 [32768, 768]); 4 channels (2 pairs)/thread.
__global__ __launch_bounds__(256) void rope_qk(short* __restrict__ q,
                                               short* __restrict__ k) {
    const long NQ = 32768L * 192;            // quads per array
    long i = (long)blockIdx.x * 256 + threadIdx.x;
    short* p = (i < NQ) ? q : k;
    long e = ((i < NQ) ? i : i - NQ) * 4;
    int d0 = (int)(e % 768);
    int t = (int)((e / 768) & 255);
    short4v v = *(short4v*)(p + e);
    float re0 = bf2f(v.x), im0 = bf2f(v.y), re1 = bf2f(v.z), im1 = bf2f(v.w);
    // theta_j = 10000^(-2j/768) = exp2(j * -2*log2(10000)/768)
    const float CE = -0.034603417655f;
    float j0 = (float)(d0 >> 1);
    float th0 = exp2f(j0 * CE);
    float th1 = exp2f((j0 + 1.0f) * CE);
    float s0, c0, s1, c1;
    sincosf((float)t * th0, &s0, &c0);
    sincosf((float)t * th1, &s1, &c1);
    short4v o;
    o.x = f2bf(re0 * c0 - im0 * s0);
    o.y = f2bf(re0 * s0 + im0 * c0);
    o.z = f2bf(re1 * c1 - im1 * s1);
    o.w = f2bf(re1 * s1 + im1 * c1);
    *(short4v*)(p + e) = o;
}

// ---------------------------------------------------------------------------
// Causal softmax: one wave per row of S [32768 rows x 256]; P bf16 out.
__global__ __launch_bounds__(256) void softmax_p(const float* __restrict__ S,
                                                 short* __restrict__ P) {
    int wv = threadIdx.x >> 6, lane = threadIdx.x & 63;
    int row = blockIdx.x * 4 + wv;
    int t = row & 255;
    f32x4 v = *(const f32x4*)(S + (long)row * 256 + lane * 4);
    float vals[4];
    float m = -1e30f;
    #pragma unroll
    for (int j = 0; j < 4; ++j) {
        int n = lane * 4 + j;
        vals[j] = (n <= t) ? v[j] : -1e30f;
        m = fmaxf(m, vals[j]);
    }
    #pragma unroll
    for (int o = 32; o; o >>= 1) m = fmaxf(m, __shfl_xor(m, o));
    float e[4], sum = 0.f;
    #pragma unroll
    for (int j = 0; j < 4; ++j) { e[j] = __expf(vals[j] - m); sum += e[j]; }
    #pragma unroll
    for (int o = 32; o; o >>= 1) sum += __shfl_xor(sum, o);
    float inv = 1.0f / sum;
    short4v o4;
    o4.x = f2bf(e[0] * inv); o4.y = f2bf(e[1] * inv);
    o4.z = f2bf(e[2] * inv); o4.w = f2bf(e[3] * inv);
    *(short4v*)(P + (long)row * 256 + lane * 4) = o4;
}

// ---------------------------------------------------------------------------
extern "C" void kernel_launch(void* const* d_in, const int* in_sizes, int n_in,
                              void* d_out, int out_size, void* d_ws, size_t ws_size,
                              hipStream_t stream) {
    const float* x  = (const float*)d_in[0];
    const float* Wq = (const float*)d_in[1];
    const float* Wk = (const float*)d_in[2];
    const float* Wv = (const float*)d_in[3];

    char* ws = (char*)d_ws;
    short* xb  = (short*)(ws);                  // 48 MB  x bf16 [32768,768]
    short* wtq = (short*)(ws + 50331648);       // 1.125 MB each, transposed bf16
    short* wtk = (short*)(ws + 51511296);
    short* wtv = (short*)(ws + 52690944);
    short* qb  = (short*)(ws + 53870592);       // 48 MB  q bf16
    short* kb  = (short*)(ws + 104202240);      // 48 MB  k bf16
    short* vt  = (short*)(ws + 154533888);      // 48 MB  v^T bf16 [128][768][256]
    float* S   = (float*)(ws + 204865536);      // 32 MB  scores fp32 [128][256][256]
    short* P   = (short*)(ws + 238419968);      // 16 MB  probs bf16

    cvt_x<<<24576, 256, 0, stream>>>(x, xb);
    dim3 gw(24, 24);
    cvt_wt<<<gw, 256, 0, stream>>>(Wq, wtq);
    cvt_wt<<<gw, 256, 0, stream>>>(Wk, wtk);
    cvt_wt<<<gw, 256, 0, stream>>>(Wv, wtv);

    dim3 g1(6, 256, 1);  // N=768/128, M=32768/128
    gemm_bt<0><<<g1, 256, 0, stream>>>(xb, wtq, qb, 32768, 768, 768, 0, 0, 0, 1.0f);
    gemm_bt<0><<<g1, 256, 0, stream>>>(xb, wtk, kb, 32768, 768, 768, 0, 0, 0, 1.0f);
    gemm_bt<1><<<g1, 256, 0, stream>>>(xb, wtv, vt, 32768, 768, 768, 0, 0, 0, 1.0f);

    rope_qk<<<49152, 256, 0, stream>>>(qb, kb);

    dim3 g2(2, 2, 128);  // S = q k^T : M=N=256, K=768, batched
    gemm_bt<2><<<g2, 256, 0, stream>>>(qb, kb, S, 256, 256, 768,
                                       196608, 196608, 65536, 0.0360843918f);

    softmax_p<<<8192, 256, 0, stream>>>(S, P);

    dim3 g3(6, 2, 128);  // out = P v : M=256, N=768, K=256, batched
    gemm_bt<2><<<g3, 256, 0, stream>>>(P, vt, (float*)d_out, 256, 768, 256,
                                       65536, 196608, 196608, 1.0f);
}

// Round 2
// 463.618 us; speedup vs baseline: 1.0903x; 1.0903x over previous
//
#include <hip/hip_runtime.h>
#include <hip/hip_bf16.h>
#include <stdint.h>

// B=128, T=256, C=768, D=768. M_total = 32768.

typedef __attribute__((ext_vector_type(8))) short short8;   // 8 x bf16 (4 VGPRs)
typedef __attribute__((ext_vector_type(4))) short short4v;  // 4 x bf16 (8B)
typedef __attribute__((ext_vector_type(4))) float f32x4;

__device__ __forceinline__ short f2bf(float f) {
    uint32_t u = __float_as_uint(f);
    u += 0x7fffu + ((u >> 16) & 1u);   // RNE
    return (short)(u >> 16);
}

// ---------------------------------------------------------------------------
// x fp32 -> bf16  (25,165,824 elements, 4/thread)
__global__ __launch_bounds__(256) void cvt_x(const float* __restrict__ x,
                                             short* __restrict__ xb) {
    long i = ((long)blockIdx.x * 256 + threadIdx.x) * 4;
    f32x4 v = *(const f32x4*)(x + i);
    short4v o;
    o.x = f2bf(v.x); o.y = f2bf(v.y); o.z = f2bf(v.z); o.w = f2bf(v.w);
    *(short4v*)(xb + i) = o;
}

// W [768,768] fp32 -> Wt [768,768] bf16 transposed (Wt[d][c] = W[c][d])
__global__ __launch_bounds__(256) void cvt_wt(const float* __restrict__ W,
                                              short* __restrict__ Wt) {
    __shared__ float tile[32][33];
    int d0 = blockIdx.x * 32, c0 = blockIdx.y * 32;
    int tr = threadIdx.x >> 5, tc = threadIdx.x & 31;
    #pragma unroll
    for (int i = 0; i < 32; i += 8)
        tile[tr + i][tc] = W[(long)(c0 + tr + i) * 768 + d0 + tc];
    __syncthreads();
    #pragma unroll
    for (int i = 0; i < 32; i += 8)
        Wt[(long)(d0 + tr + i) * 768 + c0 + tc] = f2bf(tile[tc][tr + i]);
}

// RoPE table: rt[t*384 + j] = (cos(t*theta_j), sin(t*theta_j))
__global__ __launch_bounds__(256) void rope_tab(float2* __restrict__ rt) {
    int i = blockIdx.x * 256 + threadIdx.x;   // 98304 total
    int t = i / 384, j = i - t * 384;
    const float CE = -0.034603417655f;        // -2*log2(10000)/768
    float th = exp2f((float)j * CE);
    float s, c;
    sincosf((float)t * th, &s, &c);
    rt[i] = make_float2(c, s);
}

// ---------------------------------------------------------------------------
// bf16 GEMM, C = A (M x K row-major) * B^T (B is N x K row-major)
// 128x128 tile, BK=32, 4 waves (2x2), 16x16x32 MFMA, global_load_lds w=16.
// LDS k-slot XOR swizzle: 16B unit (row r, kb) lives at slot (kb+(r>>1))&3
//   -> every ds_read_b128 quarter-wave phase covers all 8 bank groups 2x (free).
// EPI 2: fp32 row-major store, scaled           (S, final out)
// EPI 3: fused QKV epilogue: RoPE->q (C), RoPE->k (C2), v transposed (C3)
// CAUSAL 1: skip block if n0 > m0 (upper S tile, never read by softmax)
// CAUSAL 2: K limited to m0+128 (P is exactly 0 beyond causal)
template <int EPI, int CAUSAL>
__global__ __launch_bounds__(256)
void gemm_bt(const short* __restrict__ A, const short* __restrict__ B,
             void* __restrict__ C, void* __restrict__ C2, void* __restrict__ C3,
             const float2* __restrict__ rt,
             int M, int N, int K, long sA, long sB, long sC, float scale) {
    __shared__ short lA[128 * 32];
    __shared__ short lB[128 * 32];
    const int m0 = blockIdx.y * 128;
    const int n0 = blockIdx.x * 128;
    if (CAUSAL == 1 && n0 > m0) return;
    const int bz = blockIdx.z;
    const short* Ab = A + (long)bz * sA;
    const short* Bb = B + (long)bz * sB;
    const int tid = threadIdx.x;
    const int w = tid >> 6, lane = tid & 63;
    const int wm = (w >> 1) * 64;
    const int wn = (w & 1) * 64;
    // staging: lane covers (row = seg*16 + (lane>>2), kb = ((lane&3)-(lrow>>1))&3)
    const int lrow = lane >> 2;
    const int lcol = ((((lane & 3) - (lrow >> 1)) & 3)) * 8;   // shorts
    // fragment read swizzle slot: (kb + (r>>1)) & 3, kb = lane>>4, r ~ lane&15
    const int sw8 = (((lane >> 4) + ((lane & 15) >> 1)) & 3) * 8;

    const int Kend = (CAUSAL == 2) ? (m0 + 128 < K ? m0 + 128 : K) : K;

    f32x4 acc[4][4] = {};

    for (int k0 = 0; k0 < Kend; k0 += 32) {
        #pragma unroll
        for (int c2 = 0; c2 < 2; ++c2) {
            int seg = c2 * 4 + w;
            int row = seg * 16 + lrow;
            const short* ga = Ab + (long)(m0 + row) * K + k0 + lcol;
            __builtin_amdgcn_global_load_lds(
                (const __attribute__((address_space(1))) void*)ga,
                (__attribute__((address_space(3))) void*)(lA + seg * 512),
                16, 0, 0);
            const short* gb = Bb + (long)(n0 + row) * K + k0 + lcol;
            __builtin_amdgcn_global_load_lds(
                (const __attribute__((address_space(1))) void*)gb,
                (__attribute__((address_space(3))) void*)(lB + seg * 512),
                16, 0, 0);
        }
        __syncthreads();

        short8 af[4], bfr[4];
        const int ar = wm + (lane & 15);
        const int br = wn + (lane & 15);
        #pragma unroll
        for (int tmi = 0; tmi < 4; ++tmi)
            af[tmi] = *(const short8*)(lA + (ar + tmi * 16) * 32 + sw8);
        #pragma unroll
        for (int tni = 0; tni < 4; ++tni)
            bfr[tni] = *(const short8*)(lB + (br + tni * 16) * 32 + sw8);
        #pragma unroll
        for (int tmi = 0; tmi < 4; ++tmi)
            #pragma unroll
            for (int tni = 0; tni < 4; ++tni)
                acc[tmi][tni] = __builtin_amdgcn_mfma_f32_16x16x32_bf16(
                    af[tmi], bfr[tni], acc[tmi][tni], 0, 0, 0);
        __syncthreads();
    }

    // ---- epilogue; C/D layout: col = lane&15, row = (lane>>4)*4 + r
    const int r0 = wm + (lane >> 4) * 4;
    const int c0 = wn + (lane & 15);

    if (EPI == 2) {
        #pragma unroll
        for (int tmi = 0; tmi < 4; ++tmi)
            #pragma unroll
            for (int tni = 0; tni < 4; ++tni)
                #pragma unroll
                for (int r = 0; r < 4; ++r) {
                    int row = m0 + r0 + tmi * 16 + r;
                    int col = n0 + c0 + tni * 16;
                    ((float*)C)[(long)bz * sC + (long)row * N + col] =
                        acc[tmi][tni][r] * scale;
                }
    } else {  // EPI == 3 : fused QKV
        const int type = (n0 >= 1536) ? 2 : (n0 >= 768 ? 1 : 0);
        const int nl0 = n0 - type * 768;
        if (type < 2) {
            short* dst = (type == 0) ? (short*)C : (short*)C2;
            const int par = lane & 1;
            #pragma unroll
            for (int tmi = 0; tmi < 4; ++tmi)
                #pragma unroll
                for (int tni = 0; tni < 4; ++tni) {
                    int col = nl0 + c0 + tni * 16;
                    const float2* rtc = rt + (col >> 1);
                    #pragma unroll
                    for (int r = 0; r < 4; ++r) {
                        int row = m0 + r0 + tmi * 16 + r;
                        float val = acc[tmi][tni][r];
                        float pv = __shfl_xor(val, 1);
                        float2 cs = rtc[(row & 255) * 384];
                        float re = par ? pv : val;
                        float im = par ? val : pv;
                        float o = par ? (re * cs.y + im * cs.x)
                                      : (re * cs.x - im * cs.y);
                        dst[(long)row * 768 + col] = f2bf(o);
                    }
                }
        } else {
            short* vt = (short*)C3;
            #pragma unroll
            for (int tmi = 0; tmi < 4; ++tmi)
                #pragma unroll
                for (int tni = 0; tni < 4; ++tni) {
                    int col = nl0 + c0 + tni * 16;
                    #pragma unroll
                    for (int r = 0; r < 4; ++r) {
                        int row = m0 + r0 + tmi * 16 + r;
                        vt[((long)(row >> 8) * 768 + col) * 256 + (row & 255)] =
                            f2bf(acc[tmi][tni][r]);
                    }
                }
        }
    }
}

// ---------------------------------------------------------------------------
// Causal softmax: one wave per row of S [32768 x 256]; P bf16 out.
__global__ __launch_bounds__(256) void softmax_p(const float* __restrict__ S,
                                                 short* __restrict__ P) {
    int wv = threadIdx.x >> 6, lane = threadIdx.x & 63;
    int row = blockIdx.x * 4 + wv;
    int t = row & 255;
    f32x4 v = *(const f32x4*)(S + (long)row * 256 + lane * 4);
    float vals[4];
    float m = -1e30f;
    #pragma unroll
    for (int j = 0; j < 4; ++j) {
        int n = lane * 4 + j;
        vals[j] = (n <= t) ? v[j] : -1e30f;
        m = fmaxf(m, vals[j]);
    }
    #pragma unroll
    for (int o = 32; o; o >>= 1) m = fmaxf(m, __shfl_xor(m, o));
    float e[4], sum = 0.f;
    #pragma unroll
    for (int j = 0; j < 4; ++j) { e[j] = __expf(vals[j] - m); sum += e[j]; }
    #pragma unroll
    for (int o = 32; o; o >>= 1) sum += __shfl_xor(sum, o);
    float inv = 1.0f / sum;
    short4v o4;
    o4.x = f2bf(e[0] * inv); o4.y = f2bf(e[1] * inv);
    o4.z = f2bf(e[2] * inv); o4.w = f2bf(e[3] * inv);
    *(short4v*)(P + (long)row * 256 + lane * 4) = o4;
}

// ---------------------------------------------------------------------------
extern "C" void kernel_launch(void* const* d_in, const int* in_sizes, int n_in,
                              void* d_out, int out_size, void* d_ws, size_t ws_size,
                              hipStream_t stream) {
    const float* x  = (const float*)d_in[0];
    const float* Wq = (const float*)d_in[1];
    const float* Wk = (const float*)d_in[2];
    const float* Wv = (const float*)d_in[3];

    char* ws = (char*)d_ws;
    short*  xb = (short*)(ws);                   // 48 MB   x bf16 [32768,768]
    short*  wt = (short*)(ws + 50331648);        // 3.375MB Wqkv^T bf16 [2304,768]
    short*  qb = (short*)(ws + 53870592);        // 48 MB   q bf16 (roped)
    short*  kb = (short*)(ws + 104202240);       // 48 MB   k bf16 (roped)
    short*  vt = (short*)(ws + 154533888);       // 48 MB   v^T bf16 [128][768][256]
    float*  S  = (float*)(ws + 204865536);       // 32 MB   scores fp32
    short*  P  = (short*)(ws + 238419968);       // 16 MB   probs bf16
    float2* rt = (float2*)(ws + 255197184);      // 768 KB  rope table [256][384]

    cvt_x<<<24576, 256, 0, stream>>>(x, xb);
    dim3 gw(24, 24);
    cvt_wt<<<gw, 256, 0, stream>>>(Wq, wt);
    cvt_wt<<<gw, 256, 0, stream>>>(Wk, wt + 589824);
    cvt_wt<<<gw, 256, 0, stream>>>(Wv, wt + 1179648);
    rope_tab<<<384, 256, 0, stream>>>(rt);

    // Fused QKV: [32768,768] x [2304,768]^T ; epilogue does RoPE + v-transpose
    dim3 g1(18, 256, 1);
    gemm_bt<3, 0><<<g1, 256, 0, stream>>>(xb, wt, qb, kb, vt, rt,
                                          32768, 2304, 768, 0, 0, 0, 1.0f);

    // S = q k^T * scale (batched); upper tile skipped (masked anyway)
    dim3 g2(2, 2, 128);
    gemm_bt<2, 1><<<g2, 256, 0, stream>>>(qb, kb, S, nullptr, nullptr, nullptr,
                                          256, 256, 768, 196608, 196608, 65536,
                                          0.0360843918f);

    softmax_p<<<8192, 256, 0, stream>>>(S, P);

    // out = P v (batched); K limited to causal extent per m-tile
    dim3 g3(6, 2, 128);
    gemm_bt<2, 2><<<g3, 256, 0, stream>>>(P, vt, (float*)d_out, nullptr, nullptr,
                                          nullptr, 256, 768, 256, 65536, 196608,
                                          196608, 1.0f);
}

// Round 3
// 449.452 us; speedup vs baseline: 1.1247x; 1.0315x over previous
//
#include <hip/hip_runtime.h>
#include <hip/hip_bf16.h>
#include <stdint.h>

// B=128, T=256, C=768, D=768. M_total = 32768.

typedef __attribute__((ext_vector_type(8))) short short8;   // 8 x bf16 (4 VGPRs)
typedef __attribute__((ext_vector_type(4))) short short4v;  // 4 x bf16 (8B)
typedef __attribute__((ext_vector_type(4))) float f32x4;

__device__ __forceinline__ short f2bf(float f) {
    uint32_t u = __float_as_uint(f);
    u += 0x7fffu + ((u >> 16) & 1u);   // RNE
    return (short)(u >> 16);
}

// ---------------------------------------------------------------------------
__global__ __launch_bounds__(256) void cvt_x(const float* __restrict__ x,
                                             short* __restrict__ xb) {
    long i = ((long)blockIdx.x * 256 + threadIdx.x) * 4;
    f32x4 v = *(const f32x4*)(x + i);
    short4v o;
    o.x = f2bf(v.x); o.y = f2bf(v.y); o.z = f2bf(v.z); o.w = f2bf(v.w);
    *(short4v*)(xb + i) = o;
}

// W [768,768] fp32 -> Wt [768,768] bf16 transposed
__global__ __launch_bounds__(256) void cvt_wt(const float* __restrict__ W,
                                              short* __restrict__ Wt) {
    __shared__ float tile[32][33];
    int d0 = blockIdx.x * 32, c0 = blockIdx.y * 32;
    int tr = threadIdx.x >> 5, tc = threadIdx.x & 31;
    #pragma unroll
    for (int i = 0; i < 32; i += 8)
        tile[tr + i][tc] = W[(long)(c0 + tr + i) * 768 + d0 + tc];
    __syncthreads();
    #pragma unroll
    for (int i = 0; i < 32; i += 8)
        Wt[(long)(d0 + tr + i) * 768 + c0 + tc] = f2bf(tile[tc][tr + i]);
}

// RoPE table: rt[t*384 + j] = (cos, sin)
__global__ __launch_bounds__(256) void rope_tab(float2* __restrict__ rt) {
    int i = blockIdx.x * 256 + threadIdx.x;   // 98304
    int t = i / 384, j = i - t * 384;
    const float CE = -0.034603417655f;        // -2*log2(10000)/768
    float th = exp2f((float)j * CE);
    float s, c;
    sincosf((float)t * th, &s, &c);
    rt[i] = make_float2(c, s);
}

// ---------------------------------------------------------------------------
// bf16 GEMM, C = A (MxK row-major) * B^T (B is NxK row-major)
// 128x128 tile, BK=64, 4 waves (2x2), 16x16x32 MFMA, global_load_lds w=16.
// LDS row = 64 shorts (8 slots of 16B); slot swizzle phys=(logical+row)&7
//   -> staging offset seg-invariant, read phases 2-way (free per m136).
// EPI 2: fp32 store, scaled.  EPI 3: fused QKV (RoPE q,k; v transposed).
// CAUSAL 1: skip n0>m0.  CAUSAL 2: Kend=m0+128.
// SWZ: XCD-aware block remap (1=QKV 18x256, 2=S 2x2x128, 3=PV 6x2x128).
template <int EPI, int CAUSAL, int SWZ>
__global__ __launch_bounds__(256)
void gemm_bt(const short* __restrict__ A, const short* __restrict__ B,
             void* __restrict__ C, void* __restrict__ C2, void* __restrict__ C3,
             const float2* __restrict__ rt,
             int M, int N, int K, long sA, long sB, long sC, float scale) {
    int bx, by, bz;
    if (SWZ == 1) {          // grid (18,256): XCD c owns 32 contiguous A-stripes
        int p = blockIdx.x + 18 * blockIdx.y;
        int c = p & 7, j = p >> 3;          // j in [0,576)
        int st = j / 18;
        by = c * 32 + st; bx = j - st * 18; bz = 0;
    } else if (SWZ == 2) {   // grid (2,2,128): XCD c owns 16 batches
        int p = blockIdx.x + 2 * (blockIdx.y + 2 * blockIdx.z);
        int c = p & 7, j = p >> 3;          // j in [0,64)
        bz = c * 16 + (j >> 2);
        by = (j >> 1) & 1; bx = j & 1;
    } else if (SWZ == 3) {   // grid (6,2,128): XCD c owns 16 batches
        int p = blockIdx.x + 6 * (blockIdx.y + 2 * blockIdx.z);
        int c = p & 7, j = p >> 3;          // j in [0,192)
        int bt = j / 12;
        bz = c * 16 + bt;
        int t = j - bt * 12;
        by = t / 6; bx = t - (t / 6) * 6;
    } else {
        bx = blockIdx.x; by = blockIdx.y; bz = blockIdx.z;
    }
    const int m0 = by * 128;
    const int n0 = bx * 128;
    if (CAUSAL == 1 && n0 > m0) return;

    __shared__ short lA[128 * 64];
    __shared__ short lB[128 * 64];
    const short* Ab = A + (long)bz * sA;
    const short* Bb = B + (long)bz * sB;
    const int tid = threadIdx.x;
    const int w = tid >> 6, lane = tid & 63;
    const int wm = (w >> 1) * 64;
    const int wn = (w & 1) * 64;
    // staging: lane covers (row_in_seg = lane>>3, phys slot = lane&7)
    const int lrow8 = lane >> 3;
    const int lcol = (((lane & 7) - lrow8) & 7) * 8;   // logical k slot, shorts
    // frag read phys slot base (tmi-invariant since tile row step 16 = 0 mod 8)
    const int fr = lane & 15;
    const int kq = lane >> 4;

    const int Kend = (CAUSAL == 2) ? (m0 + 128 < K ? m0 + 128 : K) : K;

    f32x4 acc[4][4] = {};

    for (int k0 = 0; k0 < Kend; k0 += 64) {
        #pragma unroll
        for (int i = 0; i < 4; ++i) {
            int seg = i * 4 + w;                // 16 segs of 8 rows
            int row = seg * 8 + lrow8;
            const short* ga = Ab + (long)(m0 + row) * K + k0 + lcol;
            __builtin_amdgcn_global_load_lds(
                (const __attribute__((address_space(1))) void*)ga,
                (__attribute__((address_space(3))) void*)(lA + seg * 512),
                16, 0, 0);
            const short* gb = Bb + (long)(n0 + row) * K + k0 + lcol;
            __builtin_amdgcn_global_load_lds(
                (const __attribute__((address_space(1))) void*)gb,
                (__attribute__((address_space(3))) void*)(lB + seg * 512),
                16, 0, 0);
        }
        __syncthreads();

        #pragma unroll
        for (int c = 0; c < 2; ++c) {
            const int sphys = ((c * 4 + kq + fr) & 7) * 8;
            short8 af[4], bfr[4];
            #pragma unroll
            for (int tmi = 0; tmi < 4; ++tmi)
                af[tmi] = *(const short8*)(lA + (wm + fr + tmi * 16) * 64 + sphys);
            #pragma unroll
            for (int tni = 0; tni < 4; ++tni)
                bfr[tni] = *(const short8*)(lB + (wn + fr + tni * 16) * 64 + sphys);
            #pragma unroll
            for (int tmi = 0; tmi < 4; ++tmi)
                #pragma unroll
                for (int tni = 0; tni < 4; ++tni)
                    acc[tmi][tni] = __builtin_amdgcn_mfma_f32_16x16x32_bf16(
                        af[tmi], bfr[tni], acc[tmi][tni], 0, 0, 0);
        }
        __syncthreads();
    }

    // ---- epilogue; C/D layout: col = lane&15, row = (lane>>4)*4 + r
    const int r0 = wm + (lane >> 4) * 4;
    const int c0 = wn + (lane & 15);

    if (EPI == 2) {
        #pragma unroll
        for (int tmi = 0; tmi < 4; ++tmi)
            #pragma unroll
            for (int tni = 0; tni < 4; ++tni)
                #pragma unroll
                for (int r = 0; r < 4; ++r) {
                    int row = m0 + r0 + tmi * 16 + r;
                    int col = n0 + c0 + tni * 16;
                    ((float*)C)[(long)bz * sC + (long)row * N + col] =
                        acc[tmi][tni][r] * scale;
                }
    } else {  // EPI == 3 : fused QKV
        const int type = (n0 >= 1536) ? 2 : (n0 >= 768 ? 1 : 0);
        const int nl0 = n0 - type * 768;
        if (type < 2) {
            short* dst = (type == 0) ? (short*)C : (short*)C2;
            const int par = lane & 1;
            #pragma unroll
            for (int tmi = 0; tmi < 4; ++tmi)
                #pragma unroll
                for (int tni = 0; tni < 4; ++tni) {
                    int col = nl0 + c0 + tni * 16;
                    const float2* rtc = rt + (col >> 1);
                    #pragma unroll
                    for (int r = 0; r < 4; ++r) {
                        int row = m0 + r0 + tmi * 16 + r;
                        float val = acc[tmi][tni][r];
                        float pv = __shfl_xor(val, 1);
                        float2 cs = rtc[(row & 255) * 384];
                        float re = par ? pv : val;
                        float im = par ? val : pv;
                        float o = par ? (re * cs.y + im * cs.x)
                                      : (re * cs.x - im * cs.y);
                        dst[(long)row * 768 + col] = f2bf(o);
                    }
                }
        } else {
            short* vt = (short*)C3;
            #pragma unroll
            for (int tmi = 0; tmi < 4; ++tmi)
                #pragma unroll
                for (int tni = 0; tni < 4; ++tni) {
                    int col = nl0 + c0 + tni * 16;
                    #pragma unroll
                    for (int r = 0; r < 4; ++r) {
                        int row = m0 + r0 + tmi * 16 + r;
                        vt[((long)(row >> 8) * 768 + col) * 256 + (row & 255)] =
                            f2bf(acc[tmi][tni][r]);
                    }
                }
        }
    }
}

// ---------------------------------------------------------------------------
// Causal softmax: one wave per row of S [32768 x 256]; P bf16 out.
__global__ __launch_bounds__(256) void softmax_p(const float* __restrict__ S,
                                                 short* __restrict__ P) {
    int wv = threadIdx.x >> 6, lane = threadIdx.x & 63;
    int row = blockIdx.x * 4 + wv;
    int t = row & 255;
    f32x4 v = *(const f32x4*)(S + (long)row * 256 + lane * 4);
    float vals[4];
    float m = -1e30f;
    #pragma unroll
    for (int j = 0; j < 4; ++j) {
        int n = lane * 4 + j;
        vals[j] = (n <= t) ? v[j] : -1e30f;
        m = fmaxf(m, vals[j]);
    }
    #pragma unroll
    for (int o = 32; o; o >>= 1) m = fmaxf(m, __shfl_xor(m, o));
    float e[4], sum = 0.f;
    #pragma unroll
    for (int j = 0; j < 4; ++j) { e[j] = __expf(vals[j] - m); sum += e[j]; }
    #pragma unroll
    for (int o = 32; o; o >>= 1) sum += __shfl_xor(sum, o);
    float inv = 1.0f / sum;
    short4v o4;
    o4.x = f2bf(e[0] * inv); o4.y = f2bf(e[1] * inv);
    o4.z = f2bf(e[2] * inv); o4.w = f2bf(e[3] * inv);
    *(short4v*)(P + (long)row * 256 + lane * 4) = o4;
}

// ---------------------------------------------------------------------------
extern "C" void kernel_launch(void* const* d_in, const int* in_sizes, int n_in,
                              void* d_out, int out_size, void* d_ws, size_t ws_size,
                              hipStream_t stream) {
    const float* x  = (const float*)d_in[0];
    const float* Wq = (const float*)d_in[1];
    const float* Wk = (const float*)d_in[2];
    const float* Wv = (const float*)d_in[3];

    char* ws = (char*)d_ws;
    short*  xb = (short*)(ws);                   // 48 MB   x bf16
    short*  wt = (short*)(ws + 50331648);        // 3.375MB Wqkv^T bf16 [2304,768]
    short*  qb = (short*)(ws + 53870592);        // 48 MB   q bf16 (roped)
    short*  kb = (short*)(ws + 104202240);       // 48 MB   k bf16 (roped)
    short*  vt = (short*)(ws + 154533888);       // 48 MB   v^T bf16 [128][768][256]
    float*  S  = (float*)(ws + 204865536);       // 32 MB   scores fp32
    short*  P  = (short*)(ws + 238419968);       // 16 MB   probs bf16
    float2* rt = (float2*)(ws + 255197184);      // 768 KB  rope table

    cvt_x<<<24576, 256, 0, stream>>>(x, xb);
    dim3 gw(24, 24);
    cvt_wt<<<gw, 256, 0, stream>>>(Wq, wt);
    cvt_wt<<<gw, 256, 0, stream>>>(Wk, wt + 589824);
    cvt_wt<<<gw, 256, 0, stream>>>(Wv, wt + 1179648);
    rope_tab<<<384, 256, 0, stream>>>(rt);

    // Fused QKV: [32768,768] x [2304,768]^T, RoPE + v-transpose epilogue
    dim3 g1(18, 256, 1);
    gemm_bt<3, 0, 1><<<g1, 256, 0, stream>>>(xb, wt, qb, kb, vt, rt,
                                             32768, 2304, 768, 0, 0, 0, 1.0f);

    // S = q k^T * scale (batched); upper tiles skipped
    dim3 g2(2, 2, 128);
    gemm_bt<2, 1, 2><<<g2, 256, 0, stream>>>(qb, kb, S, nullptr, nullptr, nullptr,
                                             256, 256, 768, 196608, 196608, 65536,
                                             0.0360843918f);

    softmax_p<<<8192, 256, 0, stream>>>(S, P);

    // out = P v (batched); K limited to causal extent
    dim3 g3(6, 2, 128);
    gemm_bt<2, 2, 3><<<g3, 256, 0, stream>>>(P, vt, (float*)d_out, nullptr,
                                             nullptr, nullptr, 256, 768, 256,
                                             65536, 196608, 196608, 1.0f);
}